// Round 1
// baseline (4158.690 us; speedup 1.0000x reference)
//
#include <hip/hip_runtime.h>
#include <math.h>

#define BB 8
#define HH 128
#define WW 128
#define CC 96
#define NPIX (BB*HH*WW)          // 131072 pixels
#define EPSF 1e-5f
#define FT_SMOOTH_F 1e-5f

__device__ __forceinline__ float ftanimoto(float tpl, float tpp, float tll) {
    float num = tpl + FT_SMOOTH_F;
    float denum = 0.0f;
    float a = 1.0f;
#pragma unroll
    for (int d = 0; d < 5; ++d) {
        float bco = -(2.0f * a - 1.0f);
        denum += 1.0f / (a * (tpp + tll) + bco * tpl + FT_SMOOTH_F);
        a *= 2.0f;
    }
    return num * denum * 0.2f;
}

// ---------------------------------------------------------------------------
// Direct 3x3 SAME conv (NHWC) + BN + sigmoid.
// Block: (96, 4). Each thread: fixed co, 8 consecutive w-pixels (register
// blocked so each weight load feeds 8 FMAs). Block covers 32 pixels of one
// row. Grid: NPIX/32 = 4096 blocks.
// ---------------------------------------------------------------------------
__global__ __launch_bounds__(384) void conv_bn_sig_kernel(
    const float* __restrict__ x, const float* __restrict__ wgt,
    const float* __restrict__ g, const float* __restrict__ bta,
    const float* __restrict__ mu, const float* __restrict__ var,
    const float* __restrict__ zbuf, float* __restrict__ dst)
{
    const int co = threadIdx.x;          // 0..95
    const int ty = threadIdx.y;          // 0..3
    const int bid = blockIdx.x;
    const int w0 = (bid & 3) * 32;
    const int h  = (bid >> 2) & (HH - 1);
    const int b  = bid >> 9;
    const int wbase = w0 + ty * 8;

    float acc[8];
#pragma unroll
    for (int j = 0; j < 8; ++j) acc[j] = 0.0f;

    for (int dy = -1; dy <= 1; ++dy) {
        int hh = h + dy;
        if (hh < 0 || hh >= HH) continue;           // uniform across block
        const float* xrow = x + ((size_t)(b * HH + hh) * WW) * CC;
        for (int dx = -1; dx <= 1; ++dx) {
            const float* xp[8];
#pragma unroll
            for (int j = 0; j < 8; ++j) {
                int col = wbase + j + dx;
                xp[j] = (col >= 0 && col < WW) ? (xrow + (size_t)col * CC) : zbuf;
            }
            const float* wp = wgt + ((size_t)((dy + 1) * 3 + (dx + 1)) * CC) * CC + co;
#pragma unroll 2
            for (int ci = 0; ci < CC; ci += 4) {
                float wv0 = wp[(ci + 0) * CC];
                float wv1 = wp[(ci + 1) * CC];
                float wv2 = wp[(ci + 2) * CC];
                float wv3 = wp[(ci + 3) * CC];
#pragma unroll
                for (int j = 0; j < 8; ++j) {
                    const float4 xv = *(const float4*)(xp[j] + ci);
                    acc[j] = fmaf(xv.x, wv0, acc[j]);
                    acc[j] = fmaf(xv.y, wv1, acc[j]);
                    acc[j] = fmaf(xv.z, wv2, acc[j]);
                    acc[j] = fmaf(xv.w, wv3, acc[j]);
                }
            }
        }
    }

    float scl = g[co] * rsqrtf(var[co] + EPSF);
    float sft = bta[co] - mu[co] * scl;
    size_t orow = (size_t)(b * HH + h) * WW;
#pragma unroll
    for (int j = 0; j < 8; ++j) {
        float t = fmaf(acc[j], scl, sft);
        dst[(orow + wbase + j) * CC + co] = 1.0f / (1.0f + expf(-t));
    }
}

// ---------------------------------------------------------------------------
// Spatial attention: one wave per pixel, reduce over C=96 channels.
// ---------------------------------------------------------------------------
__global__ __launch_bounds__(256) void spatial_att_kernel(
    const float* __restrict__ q, const float* __restrict__ k,
    float* __restrict__ att)
{
    int gid = blockIdx.x * 256 + threadIdx.x;
    int pix = gid >> 6;
    int lane = threadIdx.x & 63;
    const float* qp = q + (size_t)pix * CC;
    const float* kp = k + (size_t)pix * CC;
    float qv = qp[lane], kv = kp[lane];
    float tpl = qv * kv, tpp = qv * qv, tll = kv * kv;
    if (lane < 32) {
        qv = qp[lane + 64]; kv = kp[lane + 64];
        tpl = fmaf(qv, kv, tpl); tpp = fmaf(qv, qv, tpp); tll = fmaf(kv, kv, tll);
    }
#pragma unroll
    for (int off = 32; off > 0; off >>= 1) {
        tpl += __shfl_xor(tpl, off);
        tpp += __shfl_xor(tpp, off);
        tll += __shfl_xor(tll, off);
    }
    if (lane == 0) att[pix] = ftanimoto(tpl, tpp, tll);
}

// ---------------------------------------------------------------------------
// Channel attention stage 1: per (b, slab of 256 pixels, c) partial sums.
// Grid: B*64 blocks, 128 threads (threads >= 96 idle). Coalesced over c.
// ---------------------------------------------------------------------------
__global__ __launch_bounds__(128) void chan_partial_kernel(
    const float* __restrict__ q, const float* __restrict__ k,
    float* __restrict__ part)
{
    int c = threadIdx.x;
    if (c >= CC) return;
    int b = blockIdx.x >> 6;
    int slab = blockIdx.x & 63;
    size_t p0 = (size_t)b * HH * WW + (size_t)slab * 256;
    const float* qp = q + p0 * CC + c;
    const float* kp = k + p0 * CC + c;
    float tpl = 0.f, tpp = 0.f, tll = 0.f;
    for (int p = 0; p < 256; ++p) {
        float qv = qp[(size_t)p * CC];
        float kv = kp[(size_t)p * CC];
        tpl = fmaf(qv, kv, tpl);
        tpp = fmaf(qv, qv, tpp);
        tll = fmaf(kv, kv, tll);
    }
    size_t idx = ((size_t)blockIdx.x * CC + c) * 3;
    part[idx + 0] = tpl;
    part[idx + 1] = tpp;
    part[idx + 2] = tll;
}

// ---------------------------------------------------------------------------
// Channel attention stage 2: reduce 64 partials per (b,c), compute Tanimoto.
// One block, 768 threads (b = t/96, c = t%96).
// ---------------------------------------------------------------------------
__global__ __launch_bounds__(768) void chan_final_kernel(
    const float* __restrict__ part, float* __restrict__ attc)
{
    int t = threadIdx.x;
    int b = t / CC;
    int c = t - b * CC;
    float tpl = 0.f, tpp = 0.f, tll = 0.f;
    for (int s = 0; s < 64; ++s) {
        size_t idx = (((size_t)(b * 64 + s)) * CC + c) * 3;
        tpl += part[idx + 0];
        tpp += part[idx + 1];
        tll += part[idx + 2];
    }
    attc[t] = ftanimoto(tpl, tpp, tll);
}

// ---------------------------------------------------------------------------
// Conv for v fused with the attention-combine + final BN epilogue.
// ---------------------------------------------------------------------------
__global__ __launch_bounds__(384) void conv_v_final_kernel(
    const float* __restrict__ x, const float* __restrict__ wgt,
    const float* __restrict__ g, const float* __restrict__ bta,
    const float* __restrict__ mu, const float* __restrict__ var,
    const float* __restrict__ attc, const float* __restrict__ atts,
    const float* __restrict__ gn, const float* __restrict__ bnb,
    const float* __restrict__ mn, const float* __restrict__ vn,
    const float* __restrict__ zbuf, float* __restrict__ dst)
{
    const int co = threadIdx.x;
    const int ty = threadIdx.y;
    const int bid = blockIdx.x;
    const int w0 = (bid & 3) * 32;
    const int h  = (bid >> 2) & (HH - 1);
    const int b  = bid >> 9;
    const int wbase = w0 + ty * 8;

    float acc[8];
#pragma unroll
    for (int j = 0; j < 8; ++j) acc[j] = 0.0f;

    for (int dy = -1; dy <= 1; ++dy) {
        int hh = h + dy;
        if (hh < 0 || hh >= HH) continue;
        const float* xrow = x + ((size_t)(b * HH + hh) * WW) * CC;
        for (int dx = -1; dx <= 1; ++dx) {
            const float* xp[8];
#pragma unroll
            for (int j = 0; j < 8; ++j) {
                int col = wbase + j + dx;
                xp[j] = (col >= 0 && col < WW) ? (xrow + (size_t)col * CC) : zbuf;
            }
            const float* wp = wgt + ((size_t)((dy + 1) * 3 + (dx + 1)) * CC) * CC + co;
#pragma unroll 2
            for (int ci = 0; ci < CC; ci += 4) {
                float wv0 = wp[(ci + 0) * CC];
                float wv1 = wp[(ci + 1) * CC];
                float wv2 = wp[(ci + 2) * CC];
                float wv3 = wp[(ci + 3) * CC];
#pragma unroll
                for (int j = 0; j < 8; ++j) {
                    const float4 xv = *(const float4*)(xp[j] + ci);
                    acc[j] = fmaf(xv.x, wv0, acc[j]);
                    acc[j] = fmaf(xv.y, wv1, acc[j]);
                    acc[j] = fmaf(xv.z, wv2, acc[j]);
                    acc[j] = fmaf(xv.w, wv3, acc[j]);
                }
            }
        }
    }

    float scl = g[co] * rsqrtf(var[co] + EPSF);
    float sft = bta[co] - mu[co] * scl;
    float nscl = gn[co] * rsqrtf(vn[co] + EPSF);
    float nsft = bnb[co] - mn[co] * nscl;
    float ac = attc[b * CC + co];
    size_t prow = (size_t)(b * HH + h) * WW;
#pragma unroll
    for (int j = 0; j < 8; ++j) {
        float t = fmaf(acc[j], scl, sft);
        float vsig = 1.0f / (1.0f + expf(-t));
        float att = 0.5f * (ac + atts[prow + wbase + j]);
        dst[(prow + wbase + j) * CC + co] = fmaf(att * vsig, nscl, nsft);
    }
}

__global__ void zero_kernel(float* __restrict__ p, int n)
{
    int i = blockIdx.x * 64 + threadIdx.x;
    if (i < n) p[i] = 0.0f;
}

extern "C" void kernel_launch(void* const* d_in, const int* in_sizes, int n_in,
                              void* d_out, int out_size, void* d_ws, size_t ws_size,
                              hipStream_t stream)
{
    const float* x1 = (const float*)d_in[0];
    const float* x2 = (const float*)d_in[1];
    const float* x3 = (const float*)d_in[2];
    const float* wq = (const float*)d_in[3];
    const float* gq = (const float*)d_in[4];
    const float* bq = (const float*)d_in[5];
    const float* mq = (const float*)d_in[6];
    const float* vq = (const float*)d_in[7];
    const float* wk = (const float*)d_in[8];
    const float* gk = (const float*)d_in[9];
    const float* bk = (const float*)d_in[10];
    const float* mk = (const float*)d_in[11];
    const float* vk = (const float*)d_in[12];
    const float* wv = (const float*)d_in[13];
    const float* gv = (const float*)d_in[14];
    const float* bv = (const float*)d_in[15];
    const float* mv = (const float*)d_in[16];
    const float* vv = (const float*)d_in[17];
    const float* gn = (const float*)d_in[18];
    const float* bnb = (const float*)d_in[19];
    const float* mn = (const float*)d_in[20];
    const float* vn = (const float*)d_in[21];

    float* q    = (float*)d_out;                 // d_out doubles as q-scratch
    float* ws   = (float*)d_ws;
    float* kbuf = ws;                            // NPIX*CC
    float* atts = kbuf + (size_t)NPIX * CC;      // NPIX
    float* part = atts + NPIX;                   // 512*CC*3
    float* attc = part + (size_t)512 * CC * 3;   // BB*CC
    float* zbuf = attc + BB * CC;                // CC zeros

    zero_kernel<<<2, 64, 0, stream>>>(zbuf, CC);

    dim3 cblk(96, 4);
    conv_bn_sig_kernel<<<NPIX / 32, cblk, 0, stream>>>(x1, wq, gq, bq, mq, vq, zbuf, q);
    conv_bn_sig_kernel<<<NPIX / 32, cblk, 0, stream>>>(x2, wk, gk, bk, mk, vk, zbuf, kbuf);
    spatial_att_kernel<<<NPIX / 4, 256, 0, stream>>>(q, kbuf, atts);
    chan_partial_kernel<<<BB * 64, 128, 0, stream>>>(q, kbuf, part);
    chan_final_kernel<<<1, 768, 0, stream>>>(part, attc);
    conv_v_final_kernel<<<NPIX / 32, cblk, 0, stream>>>(x3, wv, gv, bv, mv, vv,
                                                        attc, atts, gn, bnb, mn, vn,
                                                        zbuf, q);
}

// Round 2
// 411.331 us; speedup vs baseline: 10.1103x; 10.1103x over previous
//
#include <hip/hip_runtime.h>
#include <hip/hip_bf16.h>
#include <math.h>

#define BB 8
#define HH 128
#define WW 128
#define CC 96
#define NPIX (BB*HH*WW)
#define WP 130                    // W padded by 1 on each side
#define EPSF 1e-5f
#define FT_SMOOTH_F 1e-5f

typedef short short8 __attribute__((ext_vector_type(8)));
typedef float f32x4 __attribute__((ext_vector_type(4)));

#define GLDS(gp, lp) __builtin_amdgcn_global_load_lds( \
    (const __attribute__((address_space(1))) unsigned int*)(gp), \
    (__attribute__((address_space(3))) unsigned int*)(lp), 16, 0, 0)

__device__ __forceinline__ float ftanimoto(float tpl, float tpp, float tll) {
    float num = tpl + FT_SMOOTH_F;
    float denum = 0.0f;
    float a = 1.0f;
#pragma unroll
    for (int d = 0; d < 5; ++d) {
        float bco = -(2.0f * a - 1.0f);
        denum += 1.0f / (a * (tpp + tll) + bco * tpl + FT_SMOOTH_F);
        a *= 2.0f;
    }
    return num * denum * 0.2f;
}

__device__ __forceinline__ unsigned short f2bf(float f) {
    __hip_bfloat16 h = __float2bfloat16(f);
    return *(unsigned short*)&h;
}

// ---------------------------------------------------------------------------
// Cast + pad: x fp32 [8][128][128][96] -> bf16 [8][128][130][96], zero W-border.
// ---------------------------------------------------------------------------
__global__ __launch_bounds__(256) void cast_pad(const float* __restrict__ x,
                                                unsigned short* __restrict__ xp)
{
    const int tid = blockIdx.x * 256 + threadIdx.x;   // (b,h,wp,c4), c4 fastest
    const int c4 = tid % 24;
    int t = tid / 24;
    const int wp = t % WP; t /= WP;
    const int h = t % HH;
    const int b = t / HH;
    ushort4 o = {0, 0, 0, 0};
    if (wp > 0 && wp < WP - 1) {
        const float4 v = *(const float4*)(x + ((size_t)((b * HH + h) * WW) + (wp - 1)) * CC + c4 * 4);
        o.x = f2bf(v.x); o.y = f2bf(v.y); o.z = f2bf(v.z); o.w = f2bf(v.w);
    }
    *(ushort4*)(xp + (size_t)tid * 4) = o;
}

// ---------------------------------------------------------------------------
// Weight transpose+cast: w fp32 [864 k][96 co] -> wT bf16 [96 co][864 k].
// ---------------------------------------------------------------------------
__global__ __launch_bounds__(256) void cast_wT(const float* __restrict__ w,
                                               unsigned short* __restrict__ wT)
{
    const int tid = blockIdx.x * 256 + threadIdx.x;
    if (tid >= 864 * CC) return;
    const int co = tid % CC;
    const int k = tid / CC;
    wT[(size_t)co * 864 + k] = f2bf(w[tid]);
}

// ---------------------------------------------------------------------------
// Implicit-GEMM 3x3 conv, bf16 MFMA 16x16x32, fp32 accum.
// Block: 256 threads = 4 waves; M=256 pixels (two W-rows), N=96.
// Per wave: M=64 (4 m-tiles) x N=96 (6 n-tiles) = 24 accumulators.
// K-loop: 9 taps x 3 ci-chunks of 32. global_load_lds(16B) staging with
// XOR chunk swizzle so ds_read_b128 frag reads are <=2-way bank conflicts.
// FINAL=0: dst = sigmoid(bn(conv)) as bf16 (q/k). FINAL=1: fused attention
// combine + final BN, fp32 out.
// ---------------------------------------------------------------------------
template<int FINAL>
__global__ __launch_bounds__(256, 2) void conv_gemm(
    const unsigned short* __restrict__ xpad, const unsigned short* __restrict__ wT,
    const float* __restrict__ g, const float* __restrict__ bt,
    const float* __restrict__ mu, const float* __restrict__ var,
    const float* __restrict__ attc, const float* __restrict__ atts,
    const float* __restrict__ gnp, const float* __restrict__ bnbp,
    const float* __restrict__ mnp, const float* __restrict__ vnp,
    unsigned short* __restrict__ qout, float* __restrict__ fout)
{
    __shared__ __align__(16) char smem[16384 + 6144];   // A: 256x32 bf16, B: 32x96 bf16 (transposed)
    const int tid = threadIdx.x;
    const int wv = tid >> 6;
    const int L  = tid & 63;
    const int blk = blockIdx.x;
    const int b  = blk >> 6;
    const int h0 = (blk & 63) << 1;
    const int hrow = h0 + (wv >> 1);      // image row this wave's 64 pixels live in
    const int wbase = (wv & 1) << 6;      // first w of this wave's pixels

    // staging lane decomposition: row-slot r0, chunk d; swizzled source chunk
    const int r0 = L >> 2;
    const int dd = L & 3;
    const int csw = dd ^ ((r0 >> 1) & 3);

    // fragment-read lane decomposition
    const int lrow = L & 15;
    const int qq = L >> 4;
    const int roff = lrow * 64 + ((qq ^ ((lrow >> 1) & 3)) * 16);

    f32x4 acc[4][6];
#pragma unroll
    for (int mt = 0; mt < 4; ++mt)
#pragma unroll
        for (int nt = 0; nt < 6; ++nt) acc[mt][nt] = (f32x4){0.f, 0.f, 0.f, 0.f};

    char* ldsA = smem + (wv << 12);       // per-wave 64 rows x 64B
    char* ldsB = smem + 16384;            // 96 rows (co) x 64B

    for (int dy = -1; dy <= 1; ++dy) {
        const int hh = hrow + dy;
        const bool rv = (hh >= 0) && (hh < HH);    // wave-uniform
        for (int dx = -1; dx <= 1; ++dx) {
            const int tap = (dy + 1) * 3 + (dx + 1);
            for (int cc = 0; cc < 3; ++cc) {
                __syncthreads();     // previous step's reads complete
                if (rv) {
                    const unsigned short* srcA = xpad
                        + ((size_t)((b * HH + hh) * WP) + (wbase + r0 + dx + 1)) * CC
                        + cc * 32 + csw * 8;
#pragma unroll
                    for (int i = 0; i < 4; ++i)
                        GLDS(srcA + (size_t)i * (16 * CC), ldsA + i * 1024);
                }
                {
                    const unsigned short* srcB = wT
                        + (size_t)(wv * 16 + r0) * 864 + tap * CC + cc * 32 + csw * 8;
                    GLDS(srcB, ldsB + wv * 1024);
                    if (wv < 2) {
                        const unsigned short* srcB2 = wT
                            + (size_t)((4 + wv) * 16 + r0) * 864 + tap * CC + cc * 32 + csw * 8;
                        GLDS(srcB2, ldsB + (4 + wv) * 1024);
                    }
                }
                __syncthreads();     // staging visible (compiler drains vmcnt)
                if (rv) {
                    short8 af[4];
#pragma unroll
                    for (int mt = 0; mt < 4; ++mt)
                        af[mt] = *(const short8*)(ldsA + mt * 1024 + roff);
#pragma unroll
                    for (int nt = 0; nt < 6; ++nt) {
                        const short8 bf = *(const short8*)(ldsB + nt * 1024 + roff);
#pragma unroll
                        for (int mt = 0; mt < 4; ++mt)
                            acc[mt][nt] = __builtin_amdgcn_mfma_f32_16x16x32_bf16(
                                af[mt], bf, acc[mt][nt], 0, 0, 0);
                    }
                }
            }
        }
    }

    // epilogue: C layout col=lane&15, row=(lane>>4)*4+reg
#pragma unroll
    for (int nt = 0; nt < 6; ++nt) {
        const int co = nt * 16 + lrow;
        const float scl = g[co] * rsqrtf(var[co] + EPSF);
        const float sft = bt[co] - mu[co] * scl;
        float nscl = 0.f, nsft = 0.f, ac = 0.f;
        if (FINAL) {
            nscl = gnp[co] * rsqrtf(vnp[co] + EPSF);
            nsft = bnbp[co] - mnp[co] * nscl;
            ac = attc[b * CC + co];
        }
#pragma unroll
        for (int mt = 0; mt < 4; ++mt) {
#pragma unroll
            for (int r = 0; r < 4; ++r) {
                const int row = (wv << 6) + (mt << 4) + (qq << 2) + r;
                const int h = h0 + (row >> 7);
                const int w = row & 127;
                const size_t pix = (size_t)(b * HH + h) * WW + w;
                const float t = acc[mt][nt][r] * scl + sft;
                const float sig = 1.0f / (1.0f + expf(-t));
                if (!FINAL) {
                    qout[pix * CC + co] = f2bf(sig);
                } else {
                    const float att = 0.5f * (ac + atts[pix]);
                    fout[pix * CC + co] = att * sig * nscl + nsft;
                }
            }
        }
    }
}

// ---------------------------------------------------------------------------
// Spatial attention: one wave per pixel, bf16 q/k, reduce over C=96.
// ---------------------------------------------------------------------------
__global__ __launch_bounds__(256) void spatial_att(
    const unsigned short* __restrict__ qb, const unsigned short* __restrict__ kb,
    float* __restrict__ atts)
{
    const int gid = blockIdx.x * 256 + threadIdx.x;
    const int pix = gid >> 6;
    const int lane = threadIdx.x & 63;
    float tpl = 0.f, tpp = 0.f, tll = 0.f;
    if (lane < 48) {
        const unsigned int qu = ((const unsigned int*)qb)[(size_t)pix * 48 + lane];
        const unsigned int ku = ((const unsigned int*)kb)[(size_t)pix * 48 + lane];
        const float q0 = __uint_as_float(qu << 16);
        const float q1 = __uint_as_float(qu & 0xffff0000u);
        const float k0 = __uint_as_float(ku << 16);
        const float k1 = __uint_as_float(ku & 0xffff0000u);
        tpl = q0 * k0 + q1 * k1;
        tpp = q0 * q0 + q1 * q1;
        tll = k0 * k0 + k1 * k1;
    }
#pragma unroll
    for (int off = 32; off > 0; off >>= 1) {
        tpl += __shfl_xor(tpl, off);
        tpp += __shfl_xor(tpp, off);
        tll += __shfl_xor(tll, off);
    }
    if (lane == 0) atts[pix] = ftanimoto(tpl, tpp, tll);
}

// ---------------------------------------------------------------------------
// Channel attention stage 1: per (b, 256-pixel slab, c) partial sums.
// ---------------------------------------------------------------------------
__global__ __launch_bounds__(128) void chan_partial(
    const unsigned short* __restrict__ qb, const unsigned short* __restrict__ kb,
    float* __restrict__ part)
{
    const int c = threadIdx.x;
    if (c >= CC) return;
    const int b = blockIdx.x >> 6;
    const int slab = blockIdx.x & 63;
    const size_t p0 = (size_t)b * HH * WW + (size_t)slab * 256;
    const unsigned short* qp = qb + p0 * CC + c;
    const unsigned short* kp = kb + p0 * CC + c;
    float tpl = 0.f, tpp = 0.f, tll = 0.f;
    for (int p = 0; p < 256; ++p) {
        const float qv = __uint_as_float((unsigned int)qp[(size_t)p * CC] << 16);
        const float kv = __uint_as_float((unsigned int)kp[(size_t)p * CC] << 16);
        tpl = fmaf(qv, kv, tpl);
        tpp = fmaf(qv, qv, tpp);
        tll = fmaf(kv, kv, tll);
    }
    const size_t idx = ((size_t)blockIdx.x * CC + c) * 3;
    part[idx + 0] = tpl;
    part[idx + 1] = tpp;
    part[idx + 2] = tll;
}

// ---------------------------------------------------------------------------
// Channel attention stage 2: reduce 64 partials per (b,c).
// ---------------------------------------------------------------------------
__global__ __launch_bounds__(768) void chan_final(
    const float* __restrict__ part, float* __restrict__ attc)
{
    const int t = threadIdx.x;
    const int b = t / CC;
    const int c = t - b * CC;
    float tpl = 0.f, tpp = 0.f, tll = 0.f;
    for (int s = 0; s < 64; ++s) {
        const size_t idx = (((size_t)(b * 64 + s)) * CC + c) * 3;
        tpl += part[idx + 0];
        tpp += part[idx + 1];
        tll += part[idx + 2];
    }
    attc[t] = ftanimoto(tpl, tpp, tll);
}

extern "C" void kernel_launch(void* const* d_in, const int* in_sizes, int n_in,
                              void* d_out, int out_size, void* d_ws, size_t ws_size,
                              hipStream_t stream)
{
    const float* x1 = (const float*)d_in[0];
    const float* x2 = (const float*)d_in[1];
    const float* x3 = (const float*)d_in[2];
    const float* wq = (const float*)d_in[3];
    const float* gq = (const float*)d_in[4];
    const float* bq = (const float*)d_in[5];
    const float* mq = (const float*)d_in[6];
    const float* vq = (const float*)d_in[7];
    const float* wk = (const float*)d_in[8];
    const float* gk = (const float*)d_in[9];
    const float* bk = (const float*)d_in[10];
    const float* mk = (const float*)d_in[11];
    const float* vk = (const float*)d_in[12];
    const float* wvw = (const float*)d_in[13];
    const float* gv = (const float*)d_in[14];
    const float* bv = (const float*)d_in[15];
    const float* mv = (const float*)d_in[16];
    const float* vv = (const float*)d_in[17];
    const float* gn = (const float*)d_in[18];
    const float* bnb = (const float*)d_in[19];
    const float* mn = (const float*)d_in[20];
    const float* vn = (const float*)d_in[21];

    // workspace layout (26.8 MB total)
    unsigned short* xpad = (unsigned short*)d_ws;                     // 8*128*130*96 bf16
    char* wsp = (char*)d_ws + (size_t)BB * HH * WP * CC * 2;          // 25,559,040
    unsigned short* wT = (unsigned short*)wsp;                        // 96*864 bf16
    float* atts = (float*)(wsp + 864 * CC * 2);                       // NPIX fp32
    float* part = atts + NPIX;                                        // 512*96*3
    float* attc = part + (size_t)512 * CC * 3;                        // 768

    // q,k bf16 live inside d_out (exactly fills it; dead before final write)
    unsigned short* qb = (unsigned short*)d_out;
    unsigned short* kb = qb + (size_t)NPIX * CC;

    const int padBlocks = (BB * HH * WP * (CC / 4)) / 256;   // 12480
    const int wtBlocks = (864 * CC + 255) / 256;             // 324

    cast_wT<<<wtBlocks, 256, 0, stream>>>(wq, wT);
    cast_pad<<<padBlocks, 256, 0, stream>>>(x1, xpad);
    conv_gemm<0><<<512, 256, 0, stream>>>(xpad, wT, gq, bq, mq, vq,
                                          nullptr, nullptr, nullptr, nullptr, nullptr, nullptr,
                                          qb, nullptr);
    cast_wT<<<wtBlocks, 256, 0, stream>>>(wk, wT);
    cast_pad<<<padBlocks, 256, 0, stream>>>(x2, xpad);
    conv_gemm<0><<<512, 256, 0, stream>>>(xpad, wT, gk, bk, mk, vk,
                                          nullptr, nullptr, nullptr, nullptr, nullptr, nullptr,
                                          kb, nullptr);
    spatial_att<<<NPIX / 4, 256, 0, stream>>>(qb, kb, atts);
    chan_partial<<<BB * 64, 128, 0, stream>>>(qb, kb, part);
    chan_final<<<1, 768, 0, stream>>>(part, attc);
    cast_wT<<<wtBlocks, 256, 0, stream>>>(wvw, wT);
    cast_pad<<<padBlocks, 256, 0, stream>>>(x3, xpad);
    conv_gemm<1><<<512, 256, 0, stream>>>(xpad, wT, gv, bv, mv, vv,
                                          attc, atts, gn, bnb, mn, vn,
                                          nullptr, (float*)d_out);
}